// Round 1
// baseline (96.509 us; speedup 1.0000x reference)
//
#include <hip/hip_runtime.h>
#include <hip/hip_bf16.h>
#include <math.h>

#define SEQ   2048
#define H     1024
#define VOCAB 32000

__device__ inline float4 ld4(const float* p) { return *reinterpret_cast<const float4*>(p); }
__device__ inline float dot4(float4 a, float4 b) { return a.x*b.x + a.y*b.y + a.z*b.z + a.w*b.w; }

__device__ inline float waveReduceSum(float v) {
#pragma unroll
    for (int off = 32; off > 0; off >>= 1) v += __shfl_down(v, off, 64);
    return v;
}
__device__ inline float waveReduceMax(float v) {
#pragma unroll
    for (int off = 32; off > 0; off >>= 1) v = fmaxf(v, __shfl_down(v, off, 64));
    return v;
}
__device__ inline float sigmoidf(float x) { return 1.f / (1.f + expf(-x)); }

// ---------------------------------------------------------------------------
// K1: LSTM cell. One block per output element j (0..1023). f-gate skipped
// (c0 == 0). Also zeroes the u accumulator (block 0).
// ---------------------------------------------------------------------------
__global__ __launch_bounds__(256) void k_lstm(
        const float* __restrict__ emb, const float* __restrict__ lctx,
        const float* __restrict__ h0,  const float* __restrict__ W_ih,
        const float* __restrict__ W_hh, const float* __restrict__ b_ih,
        const float* __restrict__ b_hh, const int* __restrict__ widx,
        float* __restrict__ h_out, float* __restrict__ u_zero) {
    const int j = blockIdx.x;
    const int t = threadIdx.x;
    const int wid = t >> 6, lane = t & 63;

    if (j == 0) {
        for (int k = t; k < H; k += 256) u_zero[k] = 0.f;
    }

    const int w = widx[0];                       // int64 LE, value < 32000 -> low word ok
    const float* embrow = emb + (size_t)w * H;

    const int ri = j, rg = j + 2 * H, ro = j + 3 * H;
    const float* wi_i = W_ih + (size_t)ri * (2 * H);
    const float* wi_g = W_ih + (size_t)rg * (2 * H);
    const float* wi_o = W_ih + (size_t)ro * (2 * H);
    const float* wh_i = W_hh + (size_t)ri * H;
    const float* wh_g = W_hh + (size_t)rg * H;
    const float* wh_o = W_hh + (size_t)ro * H;

    float ai = 0.f, ag = 0.f, ao = 0.f;
    // W_ih part: 2048 elems; iter 0 uses emb row, iter 1 uses last_context
    {
        int e = t * 4;                            // 0..1020 -> emb row
        float4 x = ld4(embrow + e);
        ai += dot4(ld4(wi_i + e), x);
        ag += dot4(ld4(wi_g + e), x);
        ao += dot4(ld4(wi_o + e), x);
    }
    {
        int e = t * 4;                            // +1024 -> last_context
        float4 x = ld4(lctx + e);
        ai += dot4(ld4(wi_i + H + e), x);
        ag += dot4(ld4(wi_g + H + e), x);
        ao += dot4(ld4(wi_o + H + e), x);
    }
    // W_hh part: 1024 elems
    {
        int e = t * 4;
        float4 x = ld4(h0 + e);
        ai += dot4(ld4(wh_i + e), x);
        ag += dot4(ld4(wh_g + e), x);
        ao += dot4(ld4(wh_o + e), x);
    }

    ai = waveReduceSum(ai); ag = waveReduceSum(ag); ao = waveReduceSum(ao);
    __shared__ float lds[12];
    if (lane == 0) { lds[wid * 3 + 0] = ai; lds[wid * 3 + 1] = ag; lds[wid * 3 + 2] = ao; }
    __syncthreads();
    if (t == 0) {
        float gi = 0.f, gg = 0.f, go = 0.f;
        for (int q = 0; q < 4; ++q) { gi += lds[q*3]; gg += lds[q*3+1]; go += lds[q*3+2]; }
        gi += b_ih[ri] + b_hh[ri];
        gg += b_ih[rg] + b_hh[rg];
        go += b_ih[ro] + b_hh[ro];
        float c = sigmoidf(gi) * tanhf(gg);      // c0 == 0 -> f-gate dead
        h_out[j] = sigmoidf(go) * tanhf(c);
    }
}

// ---------------------------------------------------------------------------
// K2: u = Wa^T h  (column-major access, coalesced over k). Partial rows per
// block, atomicAdd into u. ba is dropped: dot(ba,h) is a constant shift
// under softmax.
// ---------------------------------------------------------------------------
__global__ __launch_bounds__(256) void k_wa(
        const float* __restrict__ Wa, const float* __restrict__ h,
        float* __restrict__ u) {
    const int k  = blockIdx.x * 256 + threadIdx.x;   // column 0..1023 (gridDim.x = 4)
    const int j0 = blockIdx.y * 32;                  // gridDim.y = 32 -> 32 rows each
    float acc = 0.f;
#pragma unroll 8
    for (int j = j0; j < j0 + 32; ++j) acc += Wa[(size_t)j * H + k] * h[j];
    atomicAdd(&u[k], acc);
}

// ---------------------------------------------------------------------------
// K3a: energies[i] = dot(enc_i, u). One wave per row.
// ---------------------------------------------------------------------------
__global__ __launch_bounds__(256) void k_energy(
        const float* __restrict__ enc, const float* __restrict__ u,
        float* __restrict__ energ) {
    const int wid = threadIdx.x >> 6, lane = threadIdx.x & 63;
    const int row = blockIdx.x * 4 + wid;            // grid 512 -> rows 0..2047
    const float* er = enc + (size_t)row * H;
    float acc = 0.f;
#pragma unroll
    for (int it = 0; it < 4; ++it) {
        int e = it * 256 + lane * 4;
        acc += dot4(ld4(er + e), ld4(u + e));
    }
    acc = waveReduceSum(acc);
    if (lane == 0) energ[row] = acc;
}

// ---------------------------------------------------------------------------
// K3b: softmax over 2048 energies (single block, 1024 threads). Also zeroes
// the context accumulator.
// ---------------------------------------------------------------------------
__global__ __launch_bounds__(1024) void k_softmax(
        const float* __restrict__ energ, float* __restrict__ attw,
        float* __restrict__ ctx_zero) {
    const int t = threadIdx.x;
    const int wid = t >> 6, lane = t & 63;
    __shared__ float red[16];

    ctx_zero[t] = 0.f;

    float e0 = energ[t], e1 = energ[t + 1024];
    float m = fmaxf(e0, e1);
    m = waveReduceMax(m);
    if (lane == 0) red[wid] = m;
    __syncthreads();
    float M = -1e30f;
    for (int q = 0; q < 16; ++q) M = fmaxf(M, red[q]);
    __syncthreads();

    float x0 = expf(e0 - M), x1 = expf(e1 - M);
    float s = x0 + x1;
    s = waveReduceSum(s);
    if (lane == 0) red[wid] = s;
    __syncthreads();
    float S = 0.f;
    for (int q = 0; q < 16; ++q) S += red[q];

    attw[t] = x0 / S;
    attw[t + 1024] = x1 / S;
}

// ---------------------------------------------------------------------------
// K3c: context = attw @ enc (column access, coalesced over k), atomicAdd.
// ---------------------------------------------------------------------------
__global__ __launch_bounds__(256) void k_context(
        const float* __restrict__ enc, const float* __restrict__ attw,
        float* __restrict__ ctx) {
    const int k  = (blockIdx.x & 3) * 256 + threadIdx.x;  // column 0..1023
    const int j0 = (blockIdx.x >> 2) * 64;                // 32 rowgroups x 64 rows
    float acc = 0.f;
#pragma unroll 8
    for (int j = j0; j < j0 + 64; ++j) acc += attw[j] * enc[(size_t)j * H + k];
    atomicAdd(&ctx[k], acc);
}

// ---------------------------------------------------------------------------
// K4: logits = Wl @ [h; context] + bl. One wave per row; 262 MB -> dominant.
// ---------------------------------------------------------------------------
__global__ __launch_bounds__(256) void k_logits(
        const float* __restrict__ Wl, const float* __restrict__ vcat,
        const float* __restrict__ bl, float* __restrict__ logits) {
    const int wid = threadIdx.x >> 6, lane = threadIdx.x & 63;
    const int row = blockIdx.x * 4 + wid;            // grid 8000 -> rows 0..31999
    const float* wr = Wl + (size_t)row * (2 * H);
    float acc = 0.f;
#pragma unroll
    for (int it = 0; it < 8; ++it) {
        int e = it * 256 + lane * 4;
        acc += dot4(ld4(wr + e), ld4(vcat + e));
    }
    acc = waveReduceSum(acc);
    if (lane == 0) logits[row] = acc + bl[row];
}

// ---------------------------------------------------------------------------
// K5: log_softmax over 32000 (single block, 1024 threads).
// ---------------------------------------------------------------------------
__global__ __launch_bounds__(1024) void k_logsoftmax(
        const float* __restrict__ logits, float* __restrict__ out) {
    const int t = threadIdx.x;
    const int wid = t >> 6, lane = t & 63;
    __shared__ float red[16];

    float m = -1e30f;
    for (int i = t; i < VOCAB; i += 1024) m = fmaxf(m, logits[i]);
    m = waveReduceMax(m);
    if (lane == 0) red[wid] = m;
    __syncthreads();
    float M = -1e30f;
    for (int q = 0; q < 16; ++q) M = fmaxf(M, red[q]);
    __syncthreads();

    float s = 0.f;
    for (int i = t; i < VOCAB; i += 1024) s += expf(logits[i] - M);
    s = waveReduceSum(s);
    if (lane == 0) red[wid] = s;
    __syncthreads();
    float S = 0.f;
    for (int q = 0; q < 16; ++q) S += red[q];

    const float lse = M + logf(S);
    for (int i = t; i < VOCAB; i += 1024) out[i] = logits[i] - lse;
}

extern "C" void kernel_launch(void* const* d_in, const int* in_sizes, int n_in,
                              void* d_out, int out_size, void* d_ws, size_t ws_size,
                              hipStream_t stream) {
    const int*   widx = (const int*)d_in[0];         // int64 LE -> low 32 bits ok
    const float* lctx = (const float*)d_in[1];
    const float* h0   = (const float*)d_in[2];
    const float* enc  = (const float*)d_in[3];
    const float* emb  = (const float*)d_in[4];
    const float* W_ih = (const float*)d_in[5];
    const float* W_hh = (const float*)d_in[6];
    const float* b_ih = (const float*)d_in[7];
    const float* b_hh = (const float*)d_in[8];
    const float* Wa   = (const float*)d_in[9];
    // d_in[10] (ba) intentionally unused: constant shift under softmax
    const float* Wl   = (const float*)d_in[11];
    const float* bl   = (const float*)d_in[12];
    float* out = (float*)d_out;

    float* ws     = (float*)d_ws;
    float* h      = ws;           // 1024   } vcat = ws[0:2048]
    float* ctx    = ws + 1024;    // 1024   }
    float* u      = ws + 2048;    // 1024
    float* energ  = ws + 3072;    // 2048
    float* attw   = ws + 5120;    // 2048
    float* logits = ws + 7168;    // 32000

    k_lstm<<<1024, 256, 0, stream>>>(emb, lctx, h0, W_ih, W_hh, b_ih, b_hh, widx, h, u);
    k_wa<<<dim3(4, 32), 256, 0, stream>>>(Wa, h, u);
    k_energy<<<512, 256, 0, stream>>>(enc, u, energ);
    k_softmax<<<1, 1024, 0, stream>>>(energ, attw, ctx);
    k_context<<<128, 256, 0, stream>>>(enc, attw, ctx);
    k_logits<<<8000, 256, 0, stream>>>(Wl, ws /*vcat*/, bl, logits);
    k_logsoftmax<<<1, 1024, 0, stream>>>(logits, out);
}